// Round 12
// baseline (159.194 us; speedup 1.0000x reference)
//
#include <hip/hip_runtime.h>
#include <hip/hip_bf16.h>
#include <math.h>

// B=2, C=128, H=W=64, heads=4, head_dim=32, kernel=7 (49 taps), depth=2.
// R30: ATTRIBUTION ROUND (code identical to R29 = best 122.9us).
// attnproj<0> and attnproj<1> are idempotent (re-run rewrites identical
// bytes), so each is launched TWICE:
//   dur = X + 2*(A0+A1);  vs  122.9 = X + A0 + A1
//   => A0+A1 = dur - 122.9;  X(xqkv_cvt) = 245.8 - dur.
// Pre-committed next step: X>50 -> attack xqkv; A0+A1>70 -> attn staging
// via global_load_lds; all ~40 -> merge to 2 kernels via halo-recompute.
#define PIX 8192
typedef __hip_bfloat16 bf16;
typedef __attribute__((ext_vector_type(8))) short short8;
typedef __attribute__((ext_vector_type(4))) float f32x4;

__device__ inline float bflo(unsigned u) { return __uint_as_float(u << 16); }
__device__ inline float bfhi(unsigned u) { return __uint_as_float(u & 0xffff0000u); }
__device__ inline unsigned short f2b(float f) {
  __hip_bfloat16 h = __float2bfloat16(f);
  return *reinterpret_cast<unsigned short*>(&h);
}
__device__ inline unsigned pack2(float a, float b) {
  return (unsigned)f2b(a) | ((unsigned)f2b(b) << 16);
}
// load 8 consecutive fp32 weights, convert to a bf16 MFMA fragment (xqkv only)
__device__ inline short8 ldw8(const float* __restrict__ p) {
  f32x4 lo = *(const f32x4*)p;
  f32x4 hi = *(const f32x4*)(p + 4);
  short8 r;
  r[0] = (short)f2b(lo[0]); r[1] = (short)f2b(lo[1]);
  r[2] = (short)f2b(lo[2]); r[3] = (short)f2b(lo[3]);
  r[4] = (short)f2b(hi[0]); r[5] = (short)f2b(hi[1]);
  r[6] = (short)f2b(hi[2]); r[7] = (short)f2b(hi[3]);
  return r;
}

// ---------- kernel 1: fused transpose+qkv0 (blocks 0..511) + weight cvt ----
__global__ __launch_bounds__(256) void xqkv_cvt(const float* __restrict__ x,
                                                const float* __restrict__ qw,
                                                const float* __restrict__ qb,
                                                unsigned short* __restrict__ qkv,
                                                const float* __restrict__ pw,
                                                unsigned short* __restrict__ wq1,
                                                unsigned short* __restrict__ wp) {
  if (blockIdx.x >= 512) {                     // weight-conversion tail blocks
    int idx = (blockIdx.x - 512) * 256 + threadIdx.x;   // 0..32767
    wq1[idx] = f2b(qw[49152 + idx]);
    wq1[idx + 16384] = f2b(qw[49152 + idx + 16384]);
    if (idx < 16384) wq1[idx + 32768] = f2b(qw[49152 + idx + 32768]);
    wp[idx] = f2b(pw[idx]);
    return;
  }

  __shared__ __align__(16) unsigned short As[16 * 136];
  int m0 = blockIdx.x * 16;
  int tid = threadIdx.x;
  int b = m0 >> 12, i = (m0 >> 6) & 63, j0 = m0 & 63;

  for (int idx = tid; idx < 2048; idx += 256) {
    int c = idx >> 4, jl = idx & 15;
    As[jl * 136 + c] =
        f2b(x[(size_t)b * 524288 + (size_t)c * 4096 + i * 64 + j0 + jl]);
  }
  __syncthreads();

  int w = tid >> 6, lane = tid & 63;
  int quad = lane >> 4, l16 = lane & 15;
  short8 a[4];
#pragma unroll
  for (int kc = 0; kc < 4; ++kc)
    a[kc] = *(const short8*)(As + l16 * 136 + kc * 32 + quad * 8);
#pragma unroll
  for (int nt = 0; nt < 6; ++nt) {
    int col = w * 96 + nt * 16 + l16;
    const float* wrow = qw + (size_t)col * 128 + quad * 8;
    f32x4 c = {0.f, 0.f, 0.f, 0.f};
#pragma unroll
    for (int kc = 0; kc < 4; ++kc)
      c = __builtin_amdgcn_mfma_f32_16x16x32_bf16(a[kc], ldw8(wrow + kc * 32), c, 0, 0, 0);
    float bv = qb[col];
#pragma unroll
    for (int r2 = 0; r2 < 4; ++r2)
      qkv[(size_t)(m0 + quad * 4 + r2) * 384 + col] = f2b(c[r2] + bv);
  }
}

// ---------- fused neighborhood attention (4 heads) + proj + epilogue ------
// Block: 4x4 px tile, ALL 4 heads, 256 threads (16 thr/px). 512 blocks =
// 2 blocks/CU co-resident (LDS 57.1KB). Phase 1: stage 100-row K/V halo.
// Phase 2: fused max-free 49-tap pass (outer loop not unrolled). Phase 3:
// pack 16x128 attn-out into kbuf, proj MFMA -> vbuf. Phase 4 (MODE 0):
// qkv1 GEMM -> qkvo. (MODE 1): LayerNorm + NCHW fp32 store.
#define RSTRIDE 136
template <int MODE>
__global__ __launch_bounds__(256, 2) void attnproj(const unsigned short* __restrict__ qkvp,
                                                   const float* __restrict__ rpb,
                                                   const unsigned short* __restrict__ wp,
                                                   const float* __restrict__ pbias,
                                                   const unsigned short* __restrict__ wq1,
                                                   const float* __restrict__ qb1,
                                                   unsigned short* __restrict__ qkvo,
                                                   const float* __restrict__ g,
                                                   const float* __restrict__ bta,
                                                   float* __restrict__ out) {
  __shared__ __align__(16) unsigned short kbuf[100 * RSTRIDE];
  __shared__ __align__(16) unsigned short vbuf[100 * RSTRIDE];
  __shared__ float rb[676];

  int ti = blockIdx.x >> 4, tj = blockIdx.x & 15;   // 16 x 16 tiles of 4x4 px
  int bz = blockIdx.y;
  int tid = threadIdx.x;
  int bi0 = ti * 4 - 3, bj0 = tj * 4 - 3;           // halo origin (10x10)

  // thread mapping (needed early for the q prefetch)
  int r = tid & 3;
  int hh = (tid >> 2) & 3;       // head 0..3
  int px = tid >> 4;             // 0..15
  int pi = px >> 2, pj = px & 3;
  int i = ti * 4 + pi, j = tj * 4 + pj;
  int pix = (bz * 64 + i) * 64 + j;
  uint4 qt = *(const uint4*)(qkvp + (size_t)pix * 384 + hh * 32 + r * 8);

  const float LOG2E = 1.44269504088896341f;
  for (int t = tid; t < 676; t += 256) rb[t] = rpb[t] * LOG2E;

  for (int t = tid; t < 3200; t += 256) {
    int row = t >> 5;            // 0..99
    int sub = t & 31;
    int isv = sub >> 4;          // 0=K, 1=V
    int c = sub & 15;            // 16 uint4 per 128-ch row
    int ri = row / 10, rj = row - ri * 10;
    int gi = bi0 + ri, gj = bj0 + rj;
    uint4 val = make_uint4(0, 0, 0, 0);
    if ((unsigned)gi < 64u && (unsigned)gj < 64u) {
      int pixn = (bz * 64 + gi) * 64 + gj;
      val = *(const uint4*)(qkvp + (size_t)pixn * 384 + 128 + isv * 128 + c * 8);
    }
    *(uint4*)((isv ? vbuf : kbuf) + row * RSTRIDE + c * 8) = val;
  }
  __syncthreads();

  int si = min(max(i - 3, 0), 57), sj = min(max(j - 3, 0), 57);
  int li = si - bi0, lj = sj - bj0;
  int oi = i - si, oj = j - sj;

  // q scale folds in log2e so exp is a bare v_exp_f32 (2^x)
  const float scale = 0.17677669529663687f * 1.44269504088896341f;
  float q[8];
  q[0] = bflo(qt.x) * scale;  q[1] = bfhi(qt.x) * scale;
  q[2] = bflo(qt.y) * scale;  q[3] = bfhi(qt.y) * scale;
  q[4] = bflo(qt.z) * scale;  q[5] = bfhi(qt.z) * scale;
  q[6] = bflo(qt.w) * scale;  q[7] = bfhi(qt.w) * scale;

  const unsigned short* kh = kbuf + hh * 32 + r * 8;
  const unsigned short* vh = vbuf + hh * 32 + r * 8;
  const float* rbh = rb + hh * 169;

  // ---- fused max-free softmax-attention: single 49-tap pass ----
  float sum = 0.f;
  float acc[8] = {0.f, 0.f, 0.f, 0.f, 0.f, 0.f, 0.f, 0.f};
#pragma unroll 1
  for (int pp = 0; pp < 7; ++pp) {
#pragma unroll
    for (int qq = 0; qq < 7; ++qq) {
      int nn = (li + pp) * 10 + (lj + qq);
      uint4 tk = *(const uint4*)(kh + nn * RSTRIDE);
      float dot = q[0] * bflo(tk.x) + q[1] * bfhi(tk.x)
                + q[2] * bflo(tk.y) + q[3] * bfhi(tk.y)
                + q[4] * bflo(tk.z) + q[5] * bfhi(tk.z)
                + q[6] * bflo(tk.w) + q[7] * bfhi(tk.w);
      dot += __shfl_xor(dot, 1);
      dot += __shfl_xor(dot, 2);
      float e = __builtin_amdgcn_exp2f(dot + rbh[(pp + 6 - oi) * 13 + (qq + 6 - oj)]);
      sum += e;
      uint4 tv = *(const uint4*)(vh + nn * RSTRIDE);
      acc[0] += e * bflo(tv.x);  acc[1] += e * bfhi(tv.x);
      acc[2] += e * bflo(tv.y);  acc[3] += e * bfhi(tv.y);
      acc[4] += e * bflo(tv.z);  acc[5] += e * bfhi(tv.z);
      acc[6] += e * bflo(tv.w);  acc[7] += e * bfhi(tv.w);
    }
  }
  float inv = 1.f / sum;
  uint4 t;
  t.x = pack2(acc[0] * inv, acc[1] * inv);
  t.y = pack2(acc[2] * inv, acc[3] * inv);
  t.z = pack2(acc[4] * inv, acc[5] * inv);
  t.w = pack2(acc[6] * inv, acc[7] * inv);
  // drain all kbuf/vbuf reads before reusing them as obuf/ybuf
  __syncthreads();
  unsigned short* obuf = kbuf;
  *(uint4*)(obuf + px * RSTRIDE + hh * 32 + r * 8) = t;
  __syncthreads();

  // ---- proj: obuf[16,128] @ Wp[128,128]^T + bias -> bf16 rows in vbuf ----
  // 4 waves: wave w -> cols [32w, 32w+32) (2 subtiles), rows = all 16.
  unsigned short* ybuf = vbuf;
  int w = tid >> 6, lane = tid & 63;
  int quad = lane >> 4, l16 = lane & 15;
  {
    short8 a[4];
#pragma unroll
    for (int kc = 0; kc < 4; ++kc)
      a[kc] = *(const short8*)(obuf + l16 * RSTRIDE + kc * 32 + quad * 8);
#pragma unroll
    for (int s = 0; s < 2; ++s) {
      int col = w * 32 + s * 16 + l16;
      const short8* bp = (const short8*)(wp + (size_t)col * 128 + quad * 8);
      f32x4 c = {0.f, 0.f, 0.f, 0.f};
#pragma unroll
      for (int kc = 0; kc < 4; ++kc)
        c = __builtin_amdgcn_mfma_f32_16x16x32_bf16(a[kc], bp[kc * 4], c, 0, 0, 0);
      float bv = pbias[col];
#pragma unroll
      for (int r2 = 0; r2 < 4; ++r2)
        ybuf[(quad * 4 + r2) * RSTRIDE + col] = f2b(c[r2] + bv);
    }
  }
  __syncthreads();

  if constexpr (MODE == 0) {
    // ---- qkv1: ybuf[16,128] @ Wq1[384,128]^T + qb1 -> qkvo (global) ----
    // 4 waves x 6 col-subtiles each (24 col-tiles x 1 row-tile).
    short8 ay[4];
#pragma unroll
    for (int kc = 0; kc < 4; ++kc)
      ay[kc] = *(const short8*)(ybuf + l16 * RSTRIDE + kc * 32 + quad * 8);
#pragma unroll
    for (int s = 0; s < 6; ++s) {
      int col = (w * 6 + s) * 16 + l16;
      const short8* bp = (const short8*)(wq1 + (size_t)col * 128 + quad * 8);
      float bv = qb1[col];
      f32x4 c = {0.f, 0.f, 0.f, 0.f};
#pragma unroll
      for (int kc = 0; kc < 4; ++kc)
        c = __builtin_amdgcn_mfma_f32_16x16x32_bf16(ay[kc], bp[kc * 4], c, 0, 0, 0);
#pragma unroll
      for (int r2 = 0; r2 < 4; ++r2) {
        int mloc = quad * 4 + r2;                          // 0..15
        int gpix = (bz * 64 + ti * 4 + (mloc >> 2)) * 64 + tj * 4 + (mloc & 3);
        qkvo[(size_t)gpix * 384 + col] = f2b(c[r2] + bv);
      }
    }
  } else {
    // ---- LayerNorm over C + transpose to (B,C,H,W) fp32 ----
    int px2 = tid >> 4, sub = tid & 15;     // 16 lanes per pixel, 16 px
    uint4 tv = *(const uint4*)(ybuf + px2 * RSTRIDE + sub * 8);
    float v[8];
    v[0] = bflo(tv.x); v[1] = bfhi(tv.x); v[2] = bflo(tv.y); v[3] = bfhi(tv.y);
    v[4] = bflo(tv.z); v[5] = bfhi(tv.z); v[6] = bflo(tv.w); v[7] = bfhi(tv.w);
    float sum2 = 0.f, sumsq = 0.f;
#pragma unroll
    for (int k = 0; k < 8; ++k) { sum2 += v[k]; sumsq += v[k] * v[k]; }
    sum2 += __shfl_xor(sum2, 1);  sumsq += __shfl_xor(sumsq, 1);
    sum2 += __shfl_xor(sum2, 2);  sumsq += __shfl_xor(sumsq, 2);
    sum2 += __shfl_xor(sum2, 4);  sumsq += __shfl_xor(sumsq, 4);
    sum2 += __shfl_xor(sum2, 8);  sumsq += __shfl_xor(sumsq, 8);
    float mu = sum2 * (1.f / 128.f);
    float rstd = rsqrtf(sumsq * (1.f / 128.f) - mu * mu + 1e-5f);
    int i2 = ti * 4 + (px2 >> 2), j2 = tj * 4 + (px2 & 3);
    int c0 = sub * 8;
    f32x4 g0 = *(const f32x4*)(g + c0),   g1 = *(const f32x4*)(g + c0 + 4);
    f32x4 b0 = *(const f32x4*)(bta + c0), b1 = *(const f32x4*)(bta + c0 + 4);
#pragma unroll
    for (int k = 0; k < 8; ++k) {
      float gg = (k < 4) ? g0[k] : g1[k - 4];
      float bb = (k < 4) ? b0[k] : b1[k - 4];
      float o = (v[k] - mu) * rstd * gg + bb;
      out[(((size_t)bz * 128 + c0 + k) * 64 + i2) * 64 + j2] = o;
    }
  }
}

extern "C" void kernel_launch(void* const* d_in, const int* in_sizes, int n_in,
                              void* d_out, int out_size, void* d_ws, size_t ws_size,
                              hipStream_t stream) {
  (void)in_sizes; (void)n_in; (void)out_size; (void)ws_size;
  const float* x   = (const float*)d_in[0];
  const float* qw  = (const float*)d_in[1];   // (2,384,128)
  const float* qb  = (const float*)d_in[2];   // (2,384)
  const float* rpb = (const float*)d_in[3];   // (2,4,13,13)
  const float* pw  = (const float*)d_in[4];   // (2,128,128)
  const float* pb  = (const float*)d_in[5];   // (2,128)
  const float* lg  = (const float*)d_in[6];
  const float* lb  = (const float*)d_in[7];

  unsigned short* qkvA = (unsigned short*)d_ws;          // PIX*384 (6 MB)
  unsigned short* qkvB = qkvA + (size_t)PIX * 384;       // PIX*384 (6 MB)
  unsigned short* wq1  = qkvB + (size_t)PIX * 384;       // 49152 (L1 qkv w)
  unsigned short* wp   = wq1 + 49152;                    // 32768 (proj w, both)
  float* out = (float*)d_out;

  xqkv_cvt<<<640, 256, 0, stream>>>(x, qw, qb, qkvA, pw, wq1, wp);
  // --- attribution: each attn kernel launched twice (idempotent) ---
  attnproj<0><<<dim3(256, 2), 256, 0, stream>>>(qkvA, rpb, wp, pb, wq1,
                                                qb + 384, qkvB, nullptr,
                                                nullptr, nullptr);
  attnproj<0><<<dim3(256, 2), 256, 0, stream>>>(qkvA, rpb, wp, pb, wq1,
                                                qb + 384, qkvB, nullptr,
                                                nullptr, nullptr);
  attnproj<1><<<dim3(256, 2), 256, 0, stream>>>(qkvB, rpb + 676, wp + 16384,
                                                pb + 128, nullptr, nullptr,
                                                nullptr, lg, lb, out);
  attnproj<1><<<dim3(256, 2), 256, 0, stream>>>(qkvB, rpb + 676, wp + 16384,
                                                pb + 128, nullptr, nullptr,
                                                nullptr, lg, lb, out);
}

// Round 13
// 122.264 us; speedup vs baseline: 1.3020x; 1.3020x over previous
//
#include <hip/hip_runtime.h>
#include <hip/hip_bf16.h>
#include <math.h>

// B=2, C=128, H=W=64, heads=4, head_dim=32, kernel=7 (49 taps), depth=2.
// Inputs fp32, OUTPUT fp32. Intermediates bf16. MFMA GEMMs.
// R31: attribution (R30) found xqkv_cvt ~= 40us (10x its modeled work);
// attnproj ~= 16us each; ~41us is a harness poison-fill baked into dur.
// xqkv_cvt replaced by: cvt_trans (pure LDS-tile transpose x->xT bf16,
// float4 loads / uint4 stores; tail blocks convert ALL weights) + standard
// gemm_mfma for qkv0 (same kernel shape as R0's fast qkv1). Rounding
// identical everywhere (f2b RNE) -> bit-identical output vs R29.
// Chain (4): cvt_trans | gemm(qkv0) | attnproj<0> | attnproj<1>.
#define PIX 8192
typedef __hip_bfloat16 bf16;
typedef __attribute__((ext_vector_type(8))) short short8;
typedef __attribute__((ext_vector_type(4))) float f32x4;

__device__ inline float bflo(unsigned u) { return __uint_as_float(u << 16); }
__device__ inline float bfhi(unsigned u) { return __uint_as_float(u & 0xffff0000u); }
__device__ inline unsigned short f2b(float f) {
  __hip_bfloat16 h = __float2bfloat16(f);
  return *reinterpret_cast<unsigned short*>(&h);
}
__device__ inline unsigned pack2(float a, float b) {
  return (unsigned)f2b(a) | ((unsigned)f2b(b) << 16);
}

// ---------- kernel 1: transpose x (NCHW fp32 -> [pix][128] bf16) + cvt w ---
// Blocks 0..511: 16 px each. Thread (c=tid>>1, half=tid&1): two float4
// loads (32B of the 64B px-row of channel c), bf16 into LDS T[px][c];
// then thread (px=tid>>4, u=tid&15) stores one uint4 -> xT row (coalesced).
// Blocks 512..639: convert qkv weights (both layers, 98304) + proj (32768).
__global__ __launch_bounds__(256) void cvt_trans(const float* __restrict__ x,
                                                 const float* __restrict__ qw,
                                                 const float* __restrict__ pw,
                                                 unsigned short* __restrict__ xT,
                                                 unsigned short* __restrict__ wq,
                                                 unsigned short* __restrict__ wp) {
  if (blockIdx.x >= 512) {                     // weight-conversion tail blocks
    int idx = (blockIdx.x - 512) * 256 + threadIdx.x;   // 0..32767
    wq[idx] = f2b(qw[idx]);
    wq[idx + 32768] = f2b(qw[idx + 32768]);
    wq[idx + 65536] = f2b(qw[idx + 65536]);
    wp[idx] = f2b(pw[idx]);
    return;
  }

  __shared__ __align__(16) unsigned short T[16][136];
  int m0 = blockIdx.x * 16;
  int tid = threadIdx.x;
  int b = m0 >> 12, i = (m0 >> 6) & 63, j0 = m0 & 63;

  int c = tid >> 1, half = tid & 1;
  const float* src = x + (size_t)b * 524288 + (size_t)c * 4096 + i * 64 + j0 + half * 8;
  f32x4 v0 = *(const f32x4*)src;
  f32x4 v1 = *(const f32x4*)(src + 4);
#pragma unroll
  for (int k = 0; k < 4; ++k) T[half * 8 + k][c] = f2b(v0[k]);
#pragma unroll
  for (int k = 0; k < 4; ++k) T[half * 8 + 4 + k][c] = f2b(v1[k]);
  __syncthreads();

  int px = tid >> 4, u = tid & 15;
  uint4 o = *(const uint4*)(&T[px][u * 8]);
  *(uint4*)(xT + (size_t)(m0 + px) * 128 + u * 8) = o;
}

// ---------- MFMA GEMM: C[M,N] = A[M,128] * W[N,128]^T + bias (bf16 W) ------
__global__ __launch_bounds__(256) void gemm_mfma(const unsigned short* __restrict__ A,
                                                 const unsigned short* __restrict__ W,
                                                 const float* __restrict__ bias,
                                                 unsigned short* __restrict__ Cmat,
                                                 int N) {
  int m0 = blockIdx.x * 64, n0 = blockIdx.y * 64;
  int tid = threadIdx.x;
  int w = tid >> 6, lane = tid & 63;
  int quad = lane >> 4, l16 = lane & 15;

  const short8* ap =
      (const short8*)(A + (size_t)(m0 + w * 16 + l16) * 128 + quad * 8);
  short8 a[4];
#pragma unroll
  for (int kc = 0; kc < 4; ++kc) a[kc] = ap[kc * 4];

  f32x4 acc[4];
#pragma unroll
  for (int nt = 0; nt < 4; ++nt) {
    const short8* bp =
        (const short8*)(W + (size_t)(n0 + nt * 16 + l16) * 128 + quad * 8);
    f32x4 c = {0.f, 0.f, 0.f, 0.f};
#pragma unroll
    for (int kc = 0; kc < 4; ++kc)
      c = __builtin_amdgcn_mfma_f32_16x16x32_bf16(a[kc], bp[kc * 4], c, 0, 0, 0);
    acc[nt] = c;
  }

#pragma unroll
  for (int nt = 0; nt < 4; ++nt) {
    int col = n0 + nt * 16 + l16;
    float bv = bias[col];
#pragma unroll
    for (int r = 0; r < 4; ++r) {
      int m = m0 + w * 16 + quad * 4 + r;
      Cmat[(size_t)m * N + col] = f2b(acc[nt][r] + bv);
    }
  }
}

// ---------- fused neighborhood attention (4 heads) + proj + epilogue ------
// (unchanged from R29) Block: 4x4 px tile, 4 heads, 256 threads; 512 blocks
// = 2 blocks/CU (LDS 57.1KB). Fused max-free 49-tap pass; proj MFMA;
// MODE 0: qkv1 GEMM -> qkvo.  MODE 1: LayerNorm + NCHW fp32 store.
#define RSTRIDE 136
template <int MODE>
__global__ __launch_bounds__(256, 2) void attnproj(const unsigned short* __restrict__ qkvp,
                                                   const float* __restrict__ rpb,
                                                   const unsigned short* __restrict__ wp,
                                                   const float* __restrict__ pbias,
                                                   const unsigned short* __restrict__ wq1,
                                                   const float* __restrict__ qb1,
                                                   unsigned short* __restrict__ qkvo,
                                                   const float* __restrict__ g,
                                                   const float* __restrict__ bta,
                                                   float* __restrict__ out) {
  __shared__ __align__(16) unsigned short kbuf[100 * RSTRIDE];
  __shared__ __align__(16) unsigned short vbuf[100 * RSTRIDE];
  __shared__ float rb[676];

  int ti = blockIdx.x >> 4, tj = blockIdx.x & 15;   // 16 x 16 tiles of 4x4 px
  int bz = blockIdx.y;
  int tid = threadIdx.x;
  int bi0 = ti * 4 - 3, bj0 = tj * 4 - 3;           // halo origin (10x10)

  int r = tid & 3;
  int hh = (tid >> 2) & 3;       // head 0..3
  int px = tid >> 4;             // 0..15
  int pi = px >> 2, pj = px & 3;
  int i = ti * 4 + pi, j = tj * 4 + pj;
  int pix = (bz * 64 + i) * 64 + j;
  uint4 qt = *(const uint4*)(qkvp + (size_t)pix * 384 + hh * 32 + r * 8);

  const float LOG2E = 1.44269504088896341f;
  for (int t = tid; t < 676; t += 256) rb[t] = rpb[t] * LOG2E;

  for (int t = tid; t < 3200; t += 256) {
    int row = t >> 5;            // 0..99
    int sub = t & 31;
    int isv = sub >> 4;          // 0=K, 1=V
    int c = sub & 15;            // 16 uint4 per 128-ch row
    int ri = row / 10, rj = row - ri * 10;
    int gi = bi0 + ri, gj = bj0 + rj;
    uint4 val = make_uint4(0, 0, 0, 0);
    if ((unsigned)gi < 64u && (unsigned)gj < 64u) {
      int pixn = (bz * 64 + gi) * 64 + gj;
      val = *(const uint4*)(qkvp + (size_t)pixn * 384 + 128 + isv * 128 + c * 8);
    }
    *(uint4*)((isv ? vbuf : kbuf) + row * RSTRIDE + c * 8) = val;
  }
  __syncthreads();

  int si = min(max(i - 3, 0), 57), sj = min(max(j - 3, 0), 57);
  int li = si - bi0, lj = sj - bj0;
  int oi = i - si, oj = j - sj;

  const float scale = 0.17677669529663687f * 1.44269504088896341f;
  float q[8];
  q[0] = bflo(qt.x) * scale;  q[1] = bfhi(qt.x) * scale;
  q[2] = bflo(qt.y) * scale;  q[3] = bfhi(qt.y) * scale;
  q[4] = bflo(qt.z) * scale;  q[5] = bfhi(qt.z) * scale;
  q[6] = bflo(qt.w) * scale;  q[7] = bfhi(qt.w) * scale;

  const unsigned short* kh = kbuf + hh * 32 + r * 8;
  const unsigned short* vh = vbuf + hh * 32 + r * 8;
  const float* rbh = rb + hh * 169;

  float sum = 0.f;
  float acc[8] = {0.f, 0.f, 0.f, 0.f, 0.f, 0.f, 0.f, 0.f};
#pragma unroll 1
  for (int pp = 0; pp < 7; ++pp) {
#pragma unroll
    for (int qq = 0; qq < 7; ++qq) {
      int nn = (li + pp) * 10 + (lj + qq);
      uint4 tk = *(const uint4*)(kh + nn * RSTRIDE);
      float dot = q[0] * bflo(tk.x) + q[1] * bfhi(tk.x)
                + q[2] * bflo(tk.y) + q[3] * bfhi(tk.y)
                + q[4] * bflo(tk.z) + q[5] * bfhi(tk.z)
                + q[6] * bflo(tk.w) + q[7] * bfhi(tk.w);
      dot += __shfl_xor(dot, 1);
      dot += __shfl_xor(dot, 2);
      float e = __builtin_amdgcn_exp2f(dot + rbh[(pp + 6 - oi) * 13 + (qq + 6 - oj)]);
      sum += e;
      uint4 tv = *(const uint4*)(vh + nn * RSTRIDE);
      acc[0] += e * bflo(tv.x);  acc[1] += e * bfhi(tv.x);
      acc[2] += e * bflo(tv.y);  acc[3] += e * bfhi(tv.y);
      acc[4] += e * bflo(tv.z);  acc[5] += e * bfhi(tv.z);
      acc[6] += e * bflo(tv.w);  acc[7] += e * bfhi(tv.w);
    }
  }
  float inv = 1.f / sum;
  uint4 t;
  t.x = pack2(acc[0] * inv, acc[1] * inv);
  t.y = pack2(acc[2] * inv, acc[3] * inv);
  t.z = pack2(acc[4] * inv, acc[5] * inv);
  t.w = pack2(acc[6] * inv, acc[7] * inv);
  __syncthreads();
  unsigned short* obuf = kbuf;
  *(uint4*)(obuf + px * RSTRIDE + hh * 32 + r * 8) = t;
  __syncthreads();

  // ---- proj: obuf[16,128] @ Wp[128,128]^T + bias -> bf16 rows in vbuf ----
  unsigned short* ybuf = vbuf;
  int w = tid >> 6, lane = tid & 63;
  int quad = lane >> 4, l16 = lane & 15;
  {
    short8 a[4];
#pragma unroll
    for (int kc = 0; kc < 4; ++kc)
      a[kc] = *(const short8*)(obuf + l16 * RSTRIDE + kc * 32 + quad * 8);
#pragma unroll
    for (int s = 0; s < 2; ++s) {
      int col = w * 32 + s * 16 + l16;
      const short8* bp = (const short8*)(wp + (size_t)col * 128 + quad * 8);
      f32x4 c = {0.f, 0.f, 0.f, 0.f};
#pragma unroll
      for (int kc = 0; kc < 4; ++kc)
        c = __builtin_amdgcn_mfma_f32_16x16x32_bf16(a[kc], bp[kc * 4], c, 0, 0, 0);
      float bv = pbias[col];
#pragma unroll
      for (int r2 = 0; r2 < 4; ++r2)
        ybuf[(quad * 4 + r2) * RSTRIDE + col] = f2b(c[r2] + bv);
    }
  }
  __syncthreads();

  if constexpr (MODE == 0) {
    // ---- qkv1: ybuf[16,128] @ Wq1[384,128]^T + qb1 -> qkvo (global) ----
    short8 ay[4];
#pragma unroll
    for (int kc = 0; kc < 4; ++kc)
      ay[kc] = *(const short8*)(ybuf + l16 * RSTRIDE + kc * 32 + quad * 8);
#pragma unroll
    for (int s = 0; s < 6; ++s) {
      int col = (w * 6 + s) * 16 + l16;
      const short8* bp = (const short8*)(wq1 + (size_t)col * 128 + quad * 8);
      float bv = qb1[col];
      f32x4 c = {0.f, 0.f, 0.f, 0.f};
#pragma unroll
      for (int kc = 0; kc < 4; ++kc)
        c = __builtin_amdgcn_mfma_f32_16x16x32_bf16(ay[kc], bp[kc * 4], c, 0, 0, 0);
#pragma unroll
      for (int r2 = 0; r2 < 4; ++r2) {
        int mloc = quad * 4 + r2;                          // 0..15
        int gpix = (bz * 64 + ti * 4 + (mloc >> 2)) * 64 + tj * 4 + (mloc & 3);
        qkvo[(size_t)gpix * 384 + col] = f2b(c[r2] + bv);
      }
    }
  } else {
    // ---- LayerNorm over C + transpose to (B,C,H,W) fp32 ----
    int px2 = tid >> 4, sub = tid & 15;     // 16 lanes per pixel, 16 px
    uint4 tv = *(const uint4*)(ybuf + px2 * RSTRIDE + sub * 8);
    float v[8];
    v[0] = bflo(tv.x); v[1] = bfhi(tv.x); v[2] = bflo(tv.y); v[3] = bfhi(tv.y);
    v[4] = bflo(tv.z); v[5] = bfhi(tv.z); v[6] = bflo(tv.w); v[7] = bfhi(tv.w);
    float sum2 = 0.f, sumsq = 0.f;
#pragma unroll
    for (int k = 0; k < 8; ++k) { sum2 += v[k]; sumsq += v[k] * v[k]; }
    sum2 += __shfl_xor(sum2, 1);  sumsq += __shfl_xor(sumsq, 1);
    sum2 += __shfl_xor(sum2, 2);  sumsq += __shfl_xor(sumsq, 2);
    sum2 += __shfl_xor(sum2, 4);  sumsq += __shfl_xor(sumsq, 4);
    sum2 += __shfl_xor(sum2, 8);  sumsq += __shfl_xor(sumsq, 8);
    float mu = sum2 * (1.f / 128.f);
    float rstd = rsqrtf(sumsq * (1.f / 128.f) - mu * mu + 1e-5f);
    int i2 = ti * 4 + (px2 >> 2), j2 = tj * 4 + (px2 & 3);
    int c0 = sub * 8;
    f32x4 g0 = *(const f32x4*)(g + c0),   g1 = *(const f32x4*)(g + c0 + 4);
    f32x4 b0 = *(const f32x4*)(bta + c0), b1 = *(const f32x4*)(bta + c0 + 4);
#pragma unroll
    for (int k = 0; k < 8; ++k) {
      float gg = (k < 4) ? g0[k] : g1[k - 4];
      float bb = (k < 4) ? b0[k] : b1[k - 4];
      float o = (v[k] - mu) * rstd * gg + bb;
      out[(((size_t)bz * 128 + c0 + k) * 64 + i2) * 64 + j2] = o;
    }
  }
}

extern "C" void kernel_launch(void* const* d_in, const int* in_sizes, int n_in,
                              void* d_out, int out_size, void* d_ws, size_t ws_size,
                              hipStream_t stream) {
  (void)in_sizes; (void)n_in; (void)out_size; (void)ws_size;
  const float* x   = (const float*)d_in[0];
  const float* qw  = (const float*)d_in[1];   // (2,384,128)
  const float* qb  = (const float*)d_in[2];   // (2,384)
  const float* rpb = (const float*)d_in[3];   // (2,4,13,13)
  const float* pw  = (const float*)d_in[4];   // (2,128,128)
  const float* pb  = (const float*)d_in[5];   // (2,128)
  const float* lg  = (const float*)d_in[6];
  const float* lb  = (const float*)d_in[7];

  unsigned short* xT   = (unsigned short*)d_ws;          // PIX*128 (2 MB)
  unsigned short* qkvA = xT + (size_t)PIX * 128;         // PIX*384 (6 MB)
  unsigned short* qkvB = qkvA + (size_t)PIX * 384;       // PIX*384 (6 MB)
  unsigned short* wq   = qkvB + (size_t)PIX * 384;       // 98304 (qkv w, both)
  unsigned short* wp   = wq + 98304;                     // 32768 (proj w, both)
  float* out = (float*)d_out;

  cvt_trans<<<640, 256, 0, stream>>>(x, qw, pw, xT, wq, wp);
  gemm_mfma<<<dim3(128, 6), 256, 0, stream>>>(xT, wq, qb, qkvA, 384);      // qkv0
  attnproj<0><<<dim3(256, 2), 256, 0, stream>>>(qkvA, rpb, wp, pb,
                                                wq + 49152, qb + 384, qkvB,
                                                nullptr, nullptr, nullptr);
  attnproj<1><<<dim3(256, 2), 256, 0, stream>>>(qkvB, rpb + 676, wp + 16384,
                                                pb + 128, nullptr, nullptr,
                                                nullptr, lg, lb, out);
}